// Round 10
// baseline (466.816 us; speedup 1.0000x reference)
//
#include <hip/hip_runtime.h>
#include <hip/hip_bf16.h>
#include <math.h>

typedef __bf16 bf16_t;
typedef __attribute__((ext_vector_type(8))) __bf16 bf16x8;
typedef __attribute__((ext_vector_type(4))) __bf16 bf16x4;
typedef __attribute__((ext_vector_type(4))) float f32x4;
typedef __attribute__((ext_vector_type(4))) unsigned u32x4;

typedef __attribute__((address_space(1))) unsigned as1u;
typedef __attribute__((address_space(3))) unsigned as3u;

#define MAXT1 68
#define MAXJ2 2560
#define G1GRID 4032   // 8 XCD slots x 9 tiles x 56 bn

__device__ __forceinline__ void async_copy16(bf16_t* lds, const bf16_t* g) {
  __builtin_amdgcn_global_load_lds((as1u*)g, (as3u*)lds, 16, 0, 0);
}

__device__ __forceinline__ float gelu_exact(float t) {
  return 0.5f * t * (1.0f + erff(t * 0.70710678118654752f));
}

__device__ __forceinline__ unsigned pack_bf16(float a, float b) {
  unsigned short ha = __builtin_bit_cast(unsigned short, (bf16_t)a);
  unsigned short hb = __builtin_bit_cast(unsigned short, (bf16_t)b);
  return (unsigned)ha | ((unsigned)hb << 16);
}

// ---------------------------------------------------------------- cast f32->bf16
__global__ __launch_bounds__(256)
void cast_kernel(const float* __restrict__ w, bf16_t* __restrict__ o, int n) {
  int i = (blockIdx.x * 256 + threadIdx.x) * 4;
  if (i < n) {
    float4 v = *(const float4*)(w + i);
    bf16x4 t;
    t[0] = (bf16_t)v.x; t[1] = (bf16_t)v.y; t[2] = (bf16_t)v.z; t[3] = (bf16_t)v.w;
    *(bf16x4*)(o + i) = t;
  }
}

// ---------------------------------------------------------------- expert sort + descriptors
// Tiles heavy-first (e=3..0), assigned round-robin to XCDs (T&7). j2 jobs written at
// p = xcd + 8*perXCD_seq (tile-major within XCD) so blockIdx%8->XCD keeps all jobs of
// a tile (shared A panel) on ONE XCD's L2. t1 consumed by gemm1's in-kernel decode.
__global__ __launch_bounds__(1024)
void sort_kernel(const int* __restrict__ em, int* __restrict__ perm,
                 int* __restrict__ t1, int* __restrict__ j2) {
  __shared__ int cnt[4], cur[4];
  __shared__ int te[MAXT1], trow[MAXT1], tnv[MAXT1], txcd[MAXT1], tjb[MAXT1];
  __shared__ int ntiles;
  const int tid = threadIdx.x;
  const int wave = tid >> 6, lane = tid & 63;
  if (tid < 4) cnt[tid] = 0;
  __syncthreads();
  for (int c = wave; c < 128; c += 16) {
    int e = em[c * 64 + lane];
    unsigned long long m0 = __ballot(e == 0), m1 = __ballot(e == 1);
    unsigned long long m2 = __ballot(e == 2), m3 = __ballot(e == 3);
    if (lane == 0) {
      atomicAdd(&cnt[0], (int)__popcll(m0)); atomicAdd(&cnt[1], (int)__popcll(m1));
      atomicAdd(&cnt[2], (int)__popcll(m2)); atomicAdd(&cnt[3], (int)__popcll(m3));
    }
  }
  __syncthreads();
  if (tid == 0) {
    cur[0] = 0; cur[1] = cnt[0]; cur[2] = cnt[0] + cnt[1]; cur[3] = cnt[0] + cnt[1] + cnt[2];
    int offp[5];
    offp[0] = 0;
    for (int e = 0; e < 4; ++e) offp[e + 1] = offp[e] + cnt[e];
    int xjobs[8] = {0, 0, 0, 0, 0, 0, 0, 0};
    int T = 0;
    for (int i = 0; i < 4; ++i) {
      int e = 3 - i;
      int nt = (cnt[e] + 127) >> 7;
      for (int loc = 0; loc < nt; ++loc) {
        te[T] = e; trow[T] = offp[e] + loc * 128;
        tnv[T] = min(128, cnt[e] - loc * 128);
        int x = T & 7;
        txcd[T] = x; tjb[T] = xjobs[x];
        xjobs[x] += (4 << e);
        ++T;
      }
    }
    ntiles = T;
  }
  __syncthreads();
  // perm scatter (grouped by expert; order within group run-varying but output-invariant)
  for (int c = wave; c < 128; c += 16) {
    int i = c * 64 + lane;
    int e = em[i];
    unsigned long long m0 = __ballot(e == 0), m1 = __ballot(e == 1);
    unsigned long long m2 = __ballot(e == 2), m3 = __ballot(e == 3);
    unsigned long long me = e == 0 ? m0 : e == 1 ? m1 : e == 2 ? m2 : m3;
    int bl = 0;
    if (lane < 4) {
      unsigned long long ml = lane == 0 ? m0 : lane == 1 ? m1 : lane == 2 ? m2 : m3;
      bl = atomicAdd(&cur[lane], (int)__popcll(ml));
    }
    int base = __shfl(bl, e);
    unsigned long long lt = (1ull << lane) - 1ull;
    perm[base + (int)__popcll(me & lt)] = i;
  }
  // t1 descriptors
  for (int t = tid; t < MAXT1; t += 1024) {
    if (t < ntiles) { t1[t * 3] = te[t]; t1[t * 3 + 1] = trow[t]; t1[t * 3 + 2] = tnv[t]; }
    else t1[t * 3] = -1;
  }
  // j2: sentinel init, then XCD-interleaved fill
  for (int j = tid; j < MAXJ2; j += 1024) j2[j * 4] = -1;
  __syncthreads();
  for (int base = 0; base < MAXT1 * 32; base += 1024) {
    int idx = base + tid;
    int T = idx >> 5, b = idx & 31;
    if (T < ntiles && b < (4 << te[T])) {
      int p = txcd[T] + 8 * (tjb[T] + b);
      if (p < MAXJ2) {
        j2[p * 4] = te[T]; j2[p * 4 + 1] = trow[T];
        j2[p * 4 + 2] = tnv[T]; j2[p * 4 + 3] = b;
      }
    }
  }
}

// ---------------------------------------------------------------- LN1 + in-mask -> bf16
__global__ __launch_bounds__(256)
void ln1_kernel(const float* __restrict__ x, const float* __restrict__ gam,
                const float* __restrict__ bet, const int* __restrict__ em,
                bf16_t* __restrict__ xn) {
  const int row = blockIdx.x, tid = threadIdx.x;
  const float4 v = ((const float4*)(x + (size_t)row * 1024))[tid];
  float s = v.x + v.y + v.z + v.w;
  float sq = v.x * v.x + v.y * v.y + v.z * v.z + v.w * v.w;
  #pragma unroll
  for (int off = 1; off < 64; off <<= 1) { s += __shfl_xor(s, off); sq += __shfl_xor(sq, off); }
  __shared__ float red[8];
  const int wave = tid >> 6, lane = tid & 63;
  if (lane == 0) { red[wave] = s; red[4 + wave] = sq; }
  __syncthreads();
  s = red[0] + red[1] + red[2] + red[3];
  sq = red[4] + red[5] + red[6] + red[7];
  const float mean = s * (1.0f / 1024.0f);
  const float var = sq * (1.0f / 1024.0f) - mean * mean;
  const float rstd = rsqrtf(var + 1e-5f);
  const int din = 1024 >> (3 - em[row]);
  const float4 gv = ((const float4*)gam)[tid];
  const float4 bv = ((const float4*)bet)[tid];
  const int c0 = tid * 4;
  float vf[4] = {v.x, v.y, v.z, v.w};
  float gf[4] = {gv.x, gv.y, gv.z, gv.w};
  float bvf[4] = {bv.x, bv.y, bv.z, bv.w};
  bf16x4 o;
  #pragma unroll
  for (int i = 0; i < 4; ++i) {
    float t = (vf[i] - mean) * rstd * gf[i] + bvf[i];
    o[i] = (c0 + i < din) ? (bf16_t)t : (bf16_t)0.0f;
  }
  *(bf16x4*)(xn + (size_t)row * 1024 + c0) = o;
}

// ---------------------------------------------------------------- LN2 over k and v, in place (bf16)
__global__ __launch_bounds__(256)
void ln2_kernel(bf16_t* __restrict__ kv, const float* __restrict__ gam,
                const float* __restrict__ bet) {
  const int row = blockIdx.x, tid = threadIdx.x;
  bf16_t* base = kv + (size_t)row * 2048;
  bf16x4 kk = *(const bf16x4*)(base + tid * 4);
  bf16x4 vv = *(const bf16x4*)(base + 1024 + tid * 4);
  float kf[4], vf[4];
  float ks = 0, ksq = 0, vs = 0, vsq = 0;
  #pragma unroll
  for (int i = 0; i < 4; ++i) {
    kf[i] = (float)kk[i]; ks += kf[i]; ksq += kf[i] * kf[i];
    vf[i] = (float)vv[i]; vs += vf[i]; vsq += vf[i] * vf[i];
  }
  #pragma unroll
  for (int off = 1; off < 64; off <<= 1) {
    ks += __shfl_xor(ks, off); ksq += __shfl_xor(ksq, off);
    vs += __shfl_xor(vs, off); vsq += __shfl_xor(vsq, off);
  }
  __shared__ float red[16];
  const int wave = tid >> 6, lane = tid & 63;
  if (lane == 0) { red[wave] = ks; red[4 + wave] = ksq; red[8 + wave] = vs; red[12 + wave] = vsq; }
  __syncthreads();
  ks = red[0] + red[1] + red[2] + red[3];
  ksq = red[4] + red[5] + red[6] + red[7];
  vs = red[8] + red[9] + red[10] + red[11];
  vsq = red[12] + red[13] + red[14] + red[15];
  const float mk = ks * (1.f / 1024.f), mv = vs * (1.f / 1024.f);
  const float rk = rsqrtf(ksq * (1.f / 1024.f) - mk * mk + 1e-5f);
  const float rv = rsqrtf(vsq * (1.f / 1024.f) - mv * mv + 1e-5f);
  const float4 gv = ((const float4*)gam)[tid];
  const float4 bv = ((const float4*)bet)[tid];
  float gf[4] = {gv.x, gv.y, gv.z, gv.w}, bvf[4] = {bv.x, bv.y, bv.z, bv.w};
  bf16x4 ko, vo;
  #pragma unroll
  for (int i = 0; i < 4; ++i) {
    ko[i] = (bf16_t)((kf[i] - mk) * rk * gf[i] + bvf[i]);
    vo[i] = (bf16_t)((vf[i] - mv) * rv * gf[i] + bvf[i]);
  }
  *(bf16x4*)(base + tid * 4) = ko;
  *(bf16x4*)(base + 1024 + tid * 4) = vo;
}

// ---------------------------------------------------------------- V transpose: kv[tok][1024+d] -> vT[bh][d][tok]
__global__ __launch_bounds__(256)
void vt_kernel(const bf16_t* __restrict__ kv, bf16_t* __restrict__ vT) {
  __shared__ bf16_t t[64][80];
  const int tt = blockIdx.x, head = blockIdx.y;
  const int tid = threadIdx.x;
  const int r8 = tid >> 3, c8 = tid & 7;
  #pragma unroll
  for (int i = 0; i < 2; ++i) {
    const int tok = i * 32 + r8;
    bf16x8 v = *(const bf16x8*)(kv + (size_t)(tt * 64 + tok) * 2048 + 1024 + head * 64 + c8 * 8);
    #pragma unroll
    for (int j = 0; j < 8; ++j) t[c8 * 8 + j][tok] = v[j];
  }
  __syncthreads();
  const int bb = tt >> 4;
  const int tloc = (tt & 15) * 64;
  #pragma unroll
  for (int i = 0; i < 2; ++i) {
    const int d = i * 32 + r8;
    bf16x8 v = *(const bf16x8*)(&t[d][c8 * 8]);
    *(bf16x8*)(vT + (size_t)((bb * 16 + head) * 64 + d) * 1024 + tloc + c8 * 8) = v;
  }
}

// ---------------------------------------------------------------- expert-sparse bf16 GEMM, 2-phase dbuf
// EPI=0: 128x128, K_e = 128<<e; 1D grid 4032, in-kernel XCD decode (t on XCD t&7, bn inner).
// EPI=1: 128x64, K=5120; jobs pre-placed by sort (tile-major per XCD).
#define STAGE(BUF, KT) do { \
    bf16_t* As_ = SMEM + (BUF) * BUFE; \
    bf16_t* Bs_ = As_ + 8192; \
    _Pragma("unroll") \
    for (int i_ = 0; i_ < 4; ++i_) \
      async_copy16(As_ + (i_ * 256 + wave * 64) * 8, Ag[i_] + (KT) * 64); \
    _Pragma("unroll") \
    for (int i_ = 0; i_ < NI; ++i_) \
      async_copy16(Bs_ + (i_ * 256 + wave * 64) * 8, Wg + (size_t)(i_ * 32) * K + (size_t)(KT) * 64); \
  } while (0)

template<int EPI>
__global__ __launch_bounds__(256)
void gemm_bt(const bf16_t* __restrict__ A, const bf16_t* __restrict__ W,
             const int* __restrict__ perm, const int* __restrict__ desc,
             const float* __restrict__ bias,
             bf16_t* __restrict__ hb, bf16_t* __restrict__ kvb,
             bf16_t* __restrict__ z) {
  constexpr int K = (EPI == 0) ? 1024 : 5120;
  constexpr int BN = (EPI == 0) ? 128 : 64;
  constexpr int NI = BN / 32;
  constexpr int WC = BN / 2;
  constexpr int BUFE = 8192 + BN * 64;

  int e, d1, nval, bn, nkt;
  if (EPI == 0) {
    const int p = blockIdx.x;
    const int x = p & 7, k = p >> 3;
    const int tloc = k / 56;
    bn = k % 56;
    const int t = tloc * 8 + x;
    if (t >= MAXT1) return;
    const int* d = desc + t * 3;
    e = d[0];
    if (e < 0) return;
    d1 = d[1]; nval = d[2]; nkt = 2 << e;
  } else {
    const int* d = desc + blockIdx.x * 4;
    e = d[0];
    if (e < 0) return;
    d1 = d[1]; nval = d[2]; bn = d[3]; nkt = 80;
  }

  __shared__ bf16_t SMEM[2 * BUFE];
  __shared__ int prow[128];
  const int tid = threadIdx.x;
  if (tid < 128) prow[tid] = perm[d1 + min(tid, nval - 1)];
  const int wave = tid >> 6, lane = tid & 63;
  const int l15 = lane & 15, l4 = lane >> 4;
  const int wm = wave >> 1, wn = wave & 1;

  f32x4 acc[4][NI] = {};

  const int rbase = tid >> 3;
  const int ss = (tid & 7) ^ (rbase & 7);
  __syncthreads();
  const bf16_t* Ag[4];
  #pragma unroll
  for (int i = 0; i < 4; ++i) Ag[i] = A + (size_t)prow[i * 32 + rbase] * K + ss * 8;
  const bf16_t* Wg = W + (size_t)(bn * BN + rbase) * K + ss * 8;

  STAGE(0, 0);
  __syncthreads();

  for (int kt = 0; kt < nkt; ++kt) {
    if (kt + 1 < nkt) STAGE((kt + 1) & 1, kt + 1);
    const bf16_t* Asr = SMEM + (kt & 1) * BUFE;
    const bf16_t* Bsr = Asr + 8192;
    #pragma unroll
    for (int ks = 0; ks < 2; ++ks) {
      bf16x8 a[4], b[NI];
      #pragma unroll
      for (int mi = 0; mi < 4; ++mi) {
        const int r = wm * 64 + mi * 16 + l15;
        const int slot = (ks * 4 + l4) ^ (r & 7);
        a[mi] = *(const bf16x8*)(Asr + r * 64 + slot * 8);
      }
      #pragma unroll
      for (int ni = 0; ni < NI; ++ni) {
        const int r = wn * WC + ni * 16 + l15;
        const int slot = (ks * 4 + l4) ^ (r & 7);
        b[ni] = *(const bf16x8*)(Bsr + r * 64 + slot * 8);
      }
      #pragma unroll
      for (int mi = 0; mi < 4; ++mi)
        #pragma unroll
        for (int ni = 0; ni < NI; ++ni)
          acc[mi][ni] = __builtin_amdgcn_mfma_f32_16x16x32_bf16(a[mi], b[ni], acc[mi][ni], 0, 0, 0);
    }
    __syncthreads();
  }

  // ---- epilogue: acc -> LDS [128][136] (fused bias/gelu), then coalesced b128 stores
  #pragma unroll
  for (int mi = 0; mi < 4; ++mi) {
    #pragma unroll
    for (int ni = 0; ni < NI; ++ni) {
      const int colf = wn * WC + ni * 16 + l15;
      #pragma unroll
      for (int r = 0; r < 4; ++r) {
        const int row = wm * 64 + mi * 16 + l4 * 4 + r;
        const float c = acc[mi][ni][r];
        bf16_t v;
        if (EPI == 0) {
          const int gc = bn * 128 + colf;
          v = (gc >= 3072) ? (bf16_t)gelu_exact(c + bias[gc - 3072]) : (bf16_t)c;
        } else {
          v = (bf16_t)(c + bias[bn * 64 + colf]);
        }
        SMEM[row * 136 + colf] = v;
      }
    }
  }
  __syncthreads();
  if (EPI == 0) {
    const int col0 = (tid & 15) * 8;
    const int gc0 = bn * 128 + col0;
    #pragma unroll
    for (int i = 0; i < 8; ++i) {
      const int row = (tid >> 4) * 8 + i;
      if (row < nval) {
        const size_t token = (size_t)prow[row];
        bf16x8 v = *(const bf16x8*)(SMEM + row * 136 + col0);
        if (gc0 < 1024)      *(bf16x8*)(hb + token * 5120 + gc0) = v;
        else if (gc0 < 3072) *(bf16x8*)(kvb + token * 2048 + (gc0 - 1024)) = v;
        else                 *(bf16x8*)(hb + token * 5120 + 1024 + (gc0 - 3072)) = v;
      }
    }
  } else {
    const int col0 = (tid & 7) * 8;
    const int gc0 = bn * 64 + col0;
    #pragma unroll
    for (int i = 0; i < 4; ++i) {
      const int row = (tid >> 3) * 4 + i;
      if (row < nval) {
        const size_t token = (size_t)prow[row];
        bf16x8 v = *(const bf16x8*)(SMEM + row * 136 + col0);
        *(bf16x8*)(z + token * 2048 + gc0) = v;
      }
    }
  }
}

// ---------------------------------------------------------------- flash attention, swapped QK^T
__global__ __launch_bounds__(256)
void attn_kernel(const bf16_t* __restrict__ kv, const bf16_t* __restrict__ vT,
                 bf16_t* __restrict__ hb) {
  __shared__ bf16_t Kl[64 * 64];
  __shared__ bf16_t Vl[64 * 64];
  const int tid = threadIdx.x;
  const int wave = tid >> 6, lane = tid & 63;
  const int l15 = lane & 15, l4 = lane >> 4;
  const int qt = blockIdx.x, bh = blockIdx.y;
  const int bb = bh >> 4;
  const int tok0 = bb << 10;
  const int d0 = (bh & 15) << 6;

  const int qrow = tok0 + qt * 64 + wave * 16 + l15;
  const bf16x8 bq0 = *(const bf16x8*)(hb + (size_t)qrow * 5120 + d0 + l4 * 8);
  const bf16x8 bq1 = *(const bf16x8*)(hb + (size_t)qrow * 5120 + d0 + 32 + l4 * 8);

  f32x4 o[4] = {};
  float mrun = -1e30f, lrun = 0.f;

  const int krb = tid >> 3;
  const int kss = (tid & 7) ^ (krb & 7);
  const int idx0 = ((2 * (l4 & 1) + 0) * 16 + l15) * 4;
  const int idx1 = ((2 * (l4 & 1) + 1) * 16 + l15) * 4;
  const bool hi = (l4 >> 1) != 0;

  for (int kt = 0; kt < 16; ++kt) {
    const int krow0 = tok0 + kt * 64;
    #pragma unroll
    for (int i = 0; i < 2; ++i) {
      async_copy16(Kl + (i * 256 + wave * 64) * 8,
                   kv + (size_t)(krow0 + i * 32 + krb) * 2048 + d0 + kss * 8);
      async_copy16(Vl + (i * 256 + wave * 64) * 8,
                   vT + (size_t)(bh * 64 + i * 32 + krb) * 1024 + kt * 64 + kss * 8);
    }
    __syncthreads();

    f32x4 s[4] = {};
    __builtin_amdgcn_s_setprio(1);
    #pragma unroll
    for (int ks = 0; ks < 2; ++ks) {
      const bf16x8 bq = ks ? bq1 : bq0;
      #pragma unroll
      for (int kc = 0; kc < 4; ++kc) {
        const int r = kc * 16 + l15;
        const int slot = (ks * 4 + l4) ^ (r & 7);
        bf16x8 ak = *(const bf16x8*)(Kl + r * 64 + slot * 8);
        s[kc] = __builtin_amdgcn_mfma_f32_16x16x32_bf16(ak, bq, s[kc], 0, 0, 0);
      }
    }
    __builtin_amdgcn_s_setprio(0);

    float mx = s[0][0];
    #pragma unroll
    for (int kc = 0; kc < 4; ++kc)
      #pragma unroll
      for (int r = 0; r < 4; ++r) mx = fmaxf(mx, s[kc][r]);
    mx = fmaxf(mx, __shfl_xor(mx, 16));
    mx = fmaxf(mx, __shfl_xor(mx, 32));
    mx *= 0.125f;
    const float mnew = fmaxf(mrun, mx);
    const float corr = __expf(mrun - mnew);
    float ps = 0.f;
    #pragma unroll
    for (int kc = 0; kc < 4; ++kc)
      #pragma unroll
      for (int r = 0; r < 4; ++r) {
        const float p = __expf(s[kc][r] * 0.125f - mnew);
        s[kc][r] = p;
        ps += p;
      }
    ps += __shfl_xor(ps, 16);
    ps += __shfl_xor(ps, 32);
    lrun = lrun * corr + ps;
    mrun = mnew;

    unsigned pd[4][2], bp[4][2][2];
    #pragma unroll
    for (int kc = 0; kc < 4; ++kc) {
      pd[kc][0] = pack_bf16(s[kc][0], s[kc][1]);
      pd[kc][1] = pack_bf16(s[kc][2], s[kc][3]);
    }
    #pragma unroll
    for (int kc = 0; kc < 4; ++kc)
      #pragma unroll
      for (int rp = 0; rp < 2; ++rp) {
        bp[kc][rp][0] = (unsigned)__builtin_amdgcn_ds_bpermute(idx0, (int)pd[kc][rp]);
        bp[kc][rp][1] = (unsigned)__builtin_amdgcn_ds_bpermute(idx1, (int)pd[kc][rp]);
      }
    u32x4 w0, w1;
    w0[0] = hi ? bp[1][0][0] : bp[0][0][0];
    w0[1] = hi ? bp[1][1][0] : bp[0][1][0];
    w0[2] = hi ? bp[1][0][1] : bp[0][0][1];
    w0[3] = hi ? bp[1][1][1] : bp[0][1][1];
    w1[0] = hi ? bp[3][0][0] : bp[2][0][0];
    w1[1] = hi ? bp[3][1][0] : bp[2][1][0];
    w1[2] = hi ? bp[3][0][1] : bp[2][0][1];
    w1[3] = hi ? bp[3][1][1] : bp[2][1][1];
    const bf16x8 pa0 = __builtin_bit_cast(bf16x8, w0);
    const bf16x8 pa1 = __builtin_bit_cast(bf16x8, w1);

    float cq[4];
    #pragma unroll
    for (int r = 0; r < 4; ++r) cq[r] = __shfl(corr, l4 * 4 + r);
    #pragma unroll
    for (int dn = 0; dn < 4; ++dn)
      #pragma unroll
      for (int r = 0; r < 4; ++r) o[dn][r] *= cq[r];

    __builtin_amdgcn_s_setprio(1);
    #pragma unroll
    for (int dn = 0; dn < 4; ++dn) {
      const int r = dn * 16 + l15;
      bf16x8 bv0 = *(const bf16x8*)(Vl + r * 64 + ((l4 ^ (r & 7)) * 8));
      bf16x8 bv1 = *(const bf16x8*)(Vl + r * 64 + (((4 + l4) ^ (r & 7)) * 8));
      o[dn] = __builtin_amdgcn_mfma_f32_16x16x32_bf16(pa0, bv0, o[dn], 0, 0, 0);
      o[dn] = __builtin_amdgcn_mfma_f32_16x16x32_bf16(pa1, bv1, o[dn], 0, 0, 0);
    }
    __builtin_amdgcn_s_setprio(0);
    __syncthreads();
  }

  const float il = 1.0f / lrun;
  float linv[4];
  #pragma unroll
  for (int r = 0; r < 4; ++r) linv[r] = __shfl(il, l4 * 4 + r);
  #pragma unroll
  for (int r = 0; r < 4; ++r) {
    const int gq = tok0 + qt * 64 + wave * 16 + l4 * 4 + r;
    #pragma unroll
    for (int dn = 0; dn < 4; ++dn)
      hb[(size_t)gq * 5120 + d0 + dn * 16 + l15] = (bf16_t)(o[dn][r] * linv[r]);
  }
}

// ---------------------------------------------------------------- final combine + tuple outputs
__global__ __launch_bounds__(256)
void final_kernel(const bf16_t* __restrict__ z, const float* __restrict__ x,
                  const int* __restrict__ em, const float* __restrict__ rp,
                  const float* __restrict__ alpha, float* __restrict__ out) {
  const int row = blockIdx.x, tid = threadIdx.x;
  const int e = em[row];
  const int dout = 2048 >> (3 - e);
  const float f = alpha[0] * rp[row * 4 + e] + 1.0f;
  const bf16x4 z0 = ((const bf16x4*)(z + (size_t)row * 2048))[tid];
  const bf16x4 z1 = ((const bf16x4*)(z + (size_t)row * 2048 + 1024))[tid];
  const float4 xv = ((const float4*)(x + (size_t)row * 1024))[tid];
  const int c = tid * 4;
  float4 o;
  o.x = ((c + 0) < dout ? (float)z0[0] : 0.f) + xv.x + f * ((1024 + c + 0) < dout ? (float)z1[0] : 0.f);
  o.y = ((c + 1) < dout ? (float)z0[1] : 0.f) + xv.y + f * ((1024 + c + 1) < dout ? (float)z1[1] : 0.f);
  o.z = ((c + 2) < dout ? (float)z0[2] : 0.f) + xv.z + f * ((1024 + c + 2) < dout ? (float)z1[2] : 0.f);
  o.w = ((c + 3) < dout ? (float)z0[3] : 0.f) + xv.w + f * ((1024 + c + 3) < dout ? (float)z1[3] : 0.f);
  ((float4*)(out + (size_t)row * 1024))[tid] = o;
  float* out_em = out + 8388608;
  float* out_rp = out_em + 8192;
  if (tid == 0) out_em[row] = (float)e;
  if (tid < 4) out_rp[row * 4 + tid] = rp[row * 4 + tid];
}

// ---------------------------------------------------------------- launch
extern "C" void kernel_launch(void* const* d_in, const int* in_sizes, int n_in,
                              void* d_out, int out_size, void* d_ws, size_t ws_size,
                              hipStream_t stream) {
  const float* x = (const float*)d_in[0];
  const int* em = (const int*)d_in[1];
  const float* rp = (const float*)d_in[2];
  const float* w_exp = (const float*)d_in[3];
  const float* mlp_bias = (const float*)d_in[4];
  const float* w_con = (const float*)d_in[5];
  const float* c_bias = (const float*)d_in[6];
  const float* n1g = (const float*)d_in[7];
  const float* n1b = (const float*)d_in[8];
  const float* n2g = (const float*)d_in[9];
  const float* n2b = (const float*)d_in[10];
  const float* alpha = (const float*)d_in[11];

  char* ws = (char*)d_ws;
  // layout (bytes), total 186,646,528:
  //   0          Wexp bf16 (14,680,064)
  //   14,680,064 xn bf16 (16,777,216) -> vT bf16 [128 bh][64 d][1024 tok] (attn)
  //   31,457,280 perm (32,768); t1 @ +32,768 (816B); j2 @ +34,816 (40,960B)
  //   48,234,496 kv bf16 (33,554,432) -> z bf16 [8192][2048] (gemm2)
  //   81,788,928 Wcon bf16 (20,971,520)
  //  102,760,448 hb bf16 [8192x5120]: cols 0-1023 q -> attn_out, 1024-5119 gelu(mlp)
  bf16_t* Wexp = (bf16_t*)ws;
  bf16_t* xn   = (bf16_t*)(ws + 14680064);
  bf16_t* vT   = (bf16_t*)(ws + 14680064);
  int*    perm = (int*)(ws + 31457280);
  int*    t1d  = (int*)(ws + 31457280 + 32768);
  int*    j2d  = (int*)(ws + 31457280 + 34816);
  bf16_t* kvb  = (bf16_t*)(ws + 48234496);
  bf16_t* z    = (bf16_t*)(ws + 48234496);
  bf16_t* Wcon = (bf16_t*)(ws + 81788928);
  bf16_t* hb   = (bf16_t*)(ws + 102760448);

  sort_kernel<<<1, 1024, 0, stream>>>(em, perm, t1d, j2d);
  cast_kernel<<<7168, 256, 0, stream>>>(w_exp, Wexp, 7340032);
  cast_kernel<<<10240, 256, 0, stream>>>(w_con, Wcon, 10485760);
  ln1_kernel<<<8192, 256, 0, stream>>>(x, n1g, n1b, em, xn);
  gemm_bt<0><<<G1GRID, 256, 0, stream>>>(xn, Wexp, perm, t1d, mlp_bias,
                                         hb, kvb, nullptr);
  ln2_kernel<<<8192, 256, 0, stream>>>(kvb, n2g, n2b);
  vt_kernel<<<dim3(128, 16), 256, 0, stream>>>(kvb, vT);
  attn_kernel<<<dim3(16, 128), 256, 0, stream>>>(kvb, vT, hb);
  gemm_bt<1><<<MAXJ2, 256, 0, stream>>>(hb, Wcon, perm, j2d, c_bias,
                                        nullptr, nullptr, z);
  final_kernel<<<8192, 256, 0, stream>>>(z, x, em, rp, alpha, (float*)d_out);
}

// Round 11
// 437.637 us; speedup vs baseline: 1.0667x; 1.0667x over previous
//
#include <hip/hip_runtime.h>
#include <hip/hip_bf16.h>
#include <math.h>

typedef __bf16 bf16_t;
typedef __attribute__((ext_vector_type(8))) __bf16 bf16x8;
typedef __attribute__((ext_vector_type(4))) __bf16 bf16x4;
typedef __attribute__((ext_vector_type(4))) float f32x4;
typedef __attribute__((ext_vector_type(4))) unsigned u32x4;

typedef __attribute__((address_space(1))) unsigned as1u;
typedef __attribute__((address_space(3))) unsigned as3u;

#define MAXT1 68
#define MAXJ2 2560

__device__ __forceinline__ void async_copy16(bf16_t* lds, const bf16_t* g) {
  __builtin_amdgcn_global_load_lds((as1u*)g, (as3u*)lds, 16, 0, 0);
}

__device__ __forceinline__ float gelu_exact(float t) {
  return 0.5f * t * (1.0f + erff(t * 0.70710678118654752f));
}

__device__ __forceinline__ unsigned pack_bf16(float a, float b) {
  unsigned short ha = __builtin_bit_cast(unsigned short, (bf16_t)a);
  unsigned short hb = __builtin_bit_cast(unsigned short, (bf16_t)b);
  return (unsigned)ha | ((unsigned)hb << 16);
}

// ---------------------------------------------------------------- cast f32->bf16
__global__ __launch_bounds__(256)
void cast_kernel(const float* __restrict__ w, bf16_t* __restrict__ o, int n) {
  int i = (blockIdx.x * 256 + threadIdx.x) * 4;
  if (i < n) {
    float4 v = *(const float4*)(w + i);
    bf16x4 t;
    t[0] = (bf16_t)v.x; t[1] = (bf16_t)v.y; t[2] = (bf16_t)v.z; t[3] = (bf16_t)v.w;
    *(bf16x4*)(o + i) = t;
  }
}

// ---------------------------------------------------------------- expert sort + descriptors
// t1: tiles heavy-first (e=3..0), consumed by gemm1's 2D grid (bn fastest -> Wexp panels
// shared machine-wide in L2/L3; FETCH ~= compulsory). j2: GEMM2 jobs written at
// p = xcd + 8*perXCD_seq (tile-major per XCD) so blockIdx%8->XCD keeps each tile's
// shared A panel on ONE XCD's L2.
__global__ __launch_bounds__(1024)
void sort_kernel(const int* __restrict__ em, int* __restrict__ perm,
                 int* __restrict__ t1, int* __restrict__ j2) {
  __shared__ int cnt[4], cur[4];
  __shared__ int te[MAXT1], trow[MAXT1], tnv[MAXT1], txcd[MAXT1], tjb[MAXT1];
  __shared__ int ntiles;
  const int tid = threadIdx.x;
  const int wave = tid >> 6, lane = tid & 63;
  if (tid < 4) cnt[tid] = 0;
  __syncthreads();
  for (int c = wave; c < 128; c += 16) {
    int e = em[c * 64 + lane];
    unsigned long long m0 = __ballot(e == 0), m1 = __ballot(e == 1);
    unsigned long long m2 = __ballot(e == 2), m3 = __ballot(e == 3);
    if (lane == 0) {
      atomicAdd(&cnt[0], (int)__popcll(m0)); atomicAdd(&cnt[1], (int)__popcll(m1));
      atomicAdd(&cnt[2], (int)__popcll(m2)); atomicAdd(&cnt[3], (int)__popcll(m3));
    }
  }
  __syncthreads();
  if (tid == 0) {
    cur[0] = 0; cur[1] = cnt[0]; cur[2] = cnt[0] + cnt[1]; cur[3] = cnt[0] + cnt[1] + cnt[2];
    int offp[5];
    offp[0] = 0;
    for (int e = 0; e < 4; ++e) offp[e + 1] = offp[e] + cnt[e];
    int xjobs[8] = {0, 0, 0, 0, 0, 0, 0, 0};
    int T = 0;
    for (int i = 0; i < 4; ++i) {
      int e = 3 - i;
      int nt = (cnt[e] + 127) >> 7;
      for (int loc = 0; loc < nt; ++loc) {
        te[T] = e; trow[T] = offp[e] + loc * 128;
        tnv[T] = min(128, cnt[e] - loc * 128);
        int x = T & 7;
        txcd[T] = x; tjb[T] = xjobs[x];
        xjobs[x] += (4 << e);
        ++T;
      }
    }
    ntiles = T;
  }
  __syncthreads();
  // perm scatter (grouped by expert; order within group run-varying but output-invariant)
  for (int c = wave; c < 128; c += 16) {
    int i = c * 64 + lane;
    int e = em[i];
    unsigned long long m0 = __ballot(e == 0), m1 = __ballot(e == 1);
    unsigned long long m2 = __ballot(e == 2), m3 = __ballot(e == 3);
    unsigned long long me = e == 0 ? m0 : e == 1 ? m1 : e == 2 ? m2 : m3;
    int bl = 0;
    if (lane < 4) {
      unsigned long long ml = lane == 0 ? m0 : lane == 1 ? m1 : lane == 2 ? m2 : m3;
      bl = atomicAdd(&cur[lane], (int)__popcll(ml));
    }
    int base = __shfl(bl, e);
    unsigned long long lt = (1ull << lane) - 1ull;
    perm[base + (int)__popcll(me & lt)] = i;
  }
  // t1 descriptors
  for (int t = tid; t < MAXT1; t += 1024) {
    if (t < ntiles) { t1[t * 3] = te[t]; t1[t * 3 + 1] = trow[t]; t1[t * 3 + 2] = tnv[t]; }
    else t1[t * 3] = -1;
  }
  // j2: sentinel init, then XCD-interleaved fill
  for (int j = tid; j < MAXJ2; j += 1024) j2[j * 4] = -1;
  __syncthreads();
  for (int base = 0; base < MAXT1 * 32; base += 1024) {
    int idx = base + tid;
    int T = idx >> 5, b = idx & 31;
    if (T < ntiles && b < (4 << te[T])) {
      int p = txcd[T] + 8 * (tjb[T] + b);
      if (p < MAXJ2) {
        j2[p * 4] = te[T]; j2[p * 4 + 1] = trow[T];
        j2[p * 4 + 2] = tnv[T]; j2[p * 4 + 3] = b;
      }
    }
  }
}

// ---------------------------------------------------------------- LN1 + in-mask -> bf16
__global__ __launch_bounds__(256)
void ln1_kernel(const float* __restrict__ x, const float* __restrict__ gam,
                const float* __restrict__ bet, const int* __restrict__ em,
                bf16_t* __restrict__ xn) {
  const int row = blockIdx.x, tid = threadIdx.x;
  const float4 v = ((const float4*)(x + (size_t)row * 1024))[tid];
  float s = v.x + v.y + v.z + v.w;
  float sq = v.x * v.x + v.y * v.y + v.z * v.z + v.w * v.w;
  #pragma unroll
  for (int off = 1; off < 64; off <<= 1) { s += __shfl_xor(s, off); sq += __shfl_xor(sq, off); }
  __shared__ float red[8];
  const int wave = tid >> 6, lane = tid & 63;
  if (lane == 0) { red[wave] = s; red[4 + wave] = sq; }
  __syncthreads();
  s = red[0] + red[1] + red[2] + red[3];
  sq = red[4] + red[5] + red[6] + red[7];
  const float mean = s * (1.0f / 1024.0f);
  const float var = sq * (1.0f / 1024.0f) - mean * mean;
  const float rstd = rsqrtf(var + 1e-5f);
  const int din = 1024 >> (3 - em[row]);
  const float4 gv = ((const float4*)gam)[tid];
  const float4 bv = ((const float4*)bet)[tid];
  const int c0 = tid * 4;
  float vf[4] = {v.x, v.y, v.z, v.w};
  float gf[4] = {gv.x, gv.y, gv.z, gv.w};
  float bvf[4] = {bv.x, bv.y, bv.z, bv.w};
  bf16x4 o;
  #pragma unroll
  for (int i = 0; i < 4; ++i) {
    float t = (vf[i] - mean) * rstd * gf[i] + bvf[i];
    o[i] = (c0 + i < din) ? (bf16_t)t : (bf16_t)0.0f;
  }
  *(bf16x4*)(xn + (size_t)row * 1024 + c0) = o;
}

// ---------------------------------------------------------------- LN2 over k and v, in place (bf16)
__global__ __launch_bounds__(256)
void ln2_kernel(bf16_t* __restrict__ kv, const float* __restrict__ gam,
                const float* __restrict__ bet) {
  const int row = blockIdx.x, tid = threadIdx.x;
  bf16_t* base = kv + (size_t)row * 2048;
  bf16x4 kk = *(const bf16x4*)(base + tid * 4);
  bf16x4 vv = *(const bf16x4*)(base + 1024 + tid * 4);
  float kf[4], vf[4];
  float ks = 0, ksq = 0, vs = 0, vsq = 0;
  #pragma unroll
  for (int i = 0; i < 4; ++i) {
    kf[i] = (float)kk[i]; ks += kf[i]; ksq += kf[i] * kf[i];
    vf[i] = (float)vv[i]; vs += vf[i]; vsq += vf[i] * vf[i];
  }
  #pragma unroll
  for (int off = 1; off < 64; off <<= 1) {
    ks += __shfl_xor(ks, off); ksq += __shfl_xor(ksq, off);
    vs += __shfl_xor(vs, off); vsq += __shfl_xor(vsq, off);
  }
  __shared__ float red[16];
  const int wave = tid >> 6, lane = tid & 63;
  if (lane == 0) { red[wave] = ks; red[4 + wave] = ksq; red[8 + wave] = vs; red[12 + wave] = vsq; }
  __syncthreads();
  ks = red[0] + red[1] + red[2] + red[3];
  ksq = red[4] + red[5] + red[6] + red[7];
  vs = red[8] + red[9] + red[10] + red[11];
  vsq = red[12] + red[13] + red[14] + red[15];
  const float mk = ks * (1.f / 1024.f), mv = vs * (1.f / 1024.f);
  const float rk = rsqrtf(ksq * (1.f / 1024.f) - mk * mk + 1e-5f);
  const float rv = rsqrtf(vsq * (1.f / 1024.f) - mv * mv + 1e-5f);
  const float4 gv = ((const float4*)gam)[tid];
  const float4 bv = ((const float4*)bet)[tid];
  float gf[4] = {gv.x, gv.y, gv.z, gv.w}, bvf[4] = {bv.x, bv.y, bv.z, bv.w};
  bf16x4 ko, vo;
  #pragma unroll
  for (int i = 0; i < 4; ++i) {
    ko[i] = (bf16_t)((kf[i] - mk) * rk * gf[i] + bvf[i]);
    vo[i] = (bf16_t)((vf[i] - mv) * rv * gf[i] + bvf[i]);
  }
  *(bf16x4*)(base + tid * 4) = ko;
  *(bf16x4*)(base + 1024 + tid * 4) = vo;
}

// ---------------------------------------------------------------- V transpose: kv[tok][1024+d] -> vT[bh][d][tok]
__global__ __launch_bounds__(256)
void vt_kernel(const bf16_t* __restrict__ kv, bf16_t* __restrict__ vT) {
  __shared__ bf16_t t[64][80];
  const int tt = blockIdx.x, head = blockIdx.y;
  const int tid = threadIdx.x;
  const int r8 = tid >> 3, c8 = tid & 7;
  #pragma unroll
  for (int i = 0; i < 2; ++i) {
    const int tok = i * 32 + r8;
    bf16x8 v = *(const bf16x8*)(kv + (size_t)(tt * 64 + tok) * 2048 + 1024 + head * 64 + c8 * 8);
    #pragma unroll
    for (int j = 0; j < 8; ++j) t[c8 * 8 + j][tok] = v[j];
  }
  __syncthreads();
  const int bb = tt >> 4;
  const int tloc = (tt & 15) * 64;
  #pragma unroll
  for (int i = 0; i < 2; ++i) {
    const int d = i * 32 + r8;
    bf16x8 v = *(const bf16x8*)(&t[d][c8 * 8]);
    *(bf16x8*)(vT + (size_t)((bb * 16 + head) * 64 + d) * 1024 + tloc + c8 * 8) = v;
  }
}

// ---------------------------------------------------------------- expert-sparse bf16 GEMM, 2-phase dbuf
// EPI=0: 128x128, K_e = 128<<e; 2D grid (56 bn fastest, 68 tiles) -- bn-fastest keeps
//        Wexp panels shared machine-wide (round-9 proven; round-10's tile-major-per-XCD
//        remap cost 9x Wexp re-fetch, 46->214MB).
// EPI=1: 128x64, K=5120; jobs pre-placed by sort (tile-major per XCD: A-panel locality).
#define STAGE(BUF, KT) do { \
    bf16_t* As_ = SMEM + (BUF) * BUFE; \
    bf16_t* Bs_ = As_ + 8192; \
    _Pragma("unroll") \
    for (int i_ = 0; i_ < 4; ++i_) \
      async_copy16(As_ + (i_ * 256 + wave * 64) * 8, Ag[i_] + (KT) * 64); \
    _Pragma("unroll") \
    for (int i_ = 0; i_ < NI; ++i_) \
      async_copy16(Bs_ + (i_ * 256 + wave * 64) * 8, Wg + (size_t)(i_ * 32) * K + (size_t)(KT) * 64); \
  } while (0)

template<int EPI>
__global__ __launch_bounds__(256)
void gemm_bt(const bf16_t* __restrict__ A, const bf16_t* __restrict__ W,
             const int* __restrict__ perm, const int* __restrict__ desc,
             const float* __restrict__ bias,
             bf16_t* __restrict__ hb, bf16_t* __restrict__ kvb,
             bf16_t* __restrict__ z) {
  constexpr int K = (EPI == 0) ? 1024 : 5120;
  constexpr int BN = (EPI == 0) ? 128 : 64;
  constexpr int NI = BN / 32;
  constexpr int WC = BN / 2;
  constexpr int BUFE = 8192 + BN * 64;

  int e, d1, nval, bn, nkt;
  if (EPI == 0) {
    const int* d = desc + blockIdx.y * 3;
    e = d[0];
    if (e < 0) return;
    d1 = d[1]; nval = d[2]; bn = blockIdx.x; nkt = 2 << e;
  } else {
    const int* d = desc + blockIdx.x * 4;
    e = d[0];
    if (e < 0) return;
    d1 = d[1]; nval = d[2]; bn = d[3]; nkt = 80;
  }

  __shared__ bf16_t SMEM[2 * BUFE];
  __shared__ int prow[128];
  const int tid = threadIdx.x;
  if (tid < 128) prow[tid] = perm[d1 + min(tid, nval - 1)];
  const int wave = tid >> 6, lane = tid & 63;
  const int l15 = lane & 15, l4 = lane >> 4;
  const int wm = wave >> 1, wn = wave & 1;

  f32x4 acc[4][NI] = {};

  const int rbase = tid >> 3;
  const int ss = (tid & 7) ^ (rbase & 7);
  __syncthreads();
  const bf16_t* Ag[4];
  #pragma unroll
  for (int i = 0; i < 4; ++i) Ag[i] = A + (size_t)prow[i * 32 + rbase] * K + ss * 8;
  const bf16_t* Wg = W + (size_t)(bn * BN + rbase) * K + ss * 8;

  STAGE(0, 0);
  __syncthreads();

  for (int kt = 0; kt < nkt; ++kt) {
    if (kt + 1 < nkt) STAGE((kt + 1) & 1, kt + 1);
    const bf16_t* Asr = SMEM + (kt & 1) * BUFE;
    const bf16_t* Bsr = Asr + 8192;
    #pragma unroll
    for (int ks = 0; ks < 2; ++ks) {
      bf16x8 a[4], b[NI];
      #pragma unroll
      for (int mi = 0; mi < 4; ++mi) {
        const int r = wm * 64 + mi * 16 + l15;
        const int slot = (ks * 4 + l4) ^ (r & 7);
        a[mi] = *(const bf16x8*)(Asr + r * 64 + slot * 8);
      }
      #pragma unroll
      for (int ni = 0; ni < NI; ++ni) {
        const int r = wn * WC + ni * 16 + l15;
        const int slot = (ks * 4 + l4) ^ (r & 7);
        b[ni] = *(const bf16x8*)(Bsr + r * 64 + slot * 8);
      }
      #pragma unroll
      for (int mi = 0; mi < 4; ++mi)
        #pragma unroll
        for (int ni = 0; ni < NI; ++ni)
          acc[mi][ni] = __builtin_amdgcn_mfma_f32_16x16x32_bf16(a[mi], b[ni], acc[mi][ni], 0, 0, 0);
    }
    __syncthreads();
  }

  // ---- epilogue: acc -> LDS [128][136] (fused bias/gelu), then coalesced b128 stores
  #pragma unroll
  for (int mi = 0; mi < 4; ++mi) {
    #pragma unroll
    for (int ni = 0; ni < NI; ++ni) {
      const int colf = wn * WC + ni * 16 + l15;
      #pragma unroll
      for (int r = 0; r < 4; ++r) {
        const int row = wm * 64 + mi * 16 + l4 * 4 + r;
        const float c = acc[mi][ni][r];
        bf16_t v;
        if (EPI == 0) {
          const int gc = bn * 128 + colf;
          v = (gc >= 3072) ? (bf16_t)gelu_exact(c + bias[gc - 3072]) : (bf16_t)c;
        } else {
          v = (bf16_t)(c + bias[bn * 64 + colf]);
        }
        SMEM[row * 136 + colf] = v;
      }
    }
  }
  __syncthreads();
  if (EPI == 0) {
    const int col0 = (tid & 15) * 8;
    const int gc0 = bn * 128 + col0;
    #pragma unroll
    for (int i = 0; i < 8; ++i) {
      const int row = (tid >> 4) * 8 + i;
      if (row < nval) {
        const size_t token = (size_t)prow[row];
        bf16x8 v = *(const bf16x8*)(SMEM + row * 136 + col0);
        if (gc0 < 1024)      *(bf16x8*)(hb + token * 5120 + gc0) = v;
        else if (gc0 < 3072) *(bf16x8*)(kvb + token * 2048 + (gc0 - 1024)) = v;
        else                 *(bf16x8*)(hb + token * 5120 + 1024 + (gc0 - 3072)) = v;
      }
    }
  } else {
    const int col0 = (tid & 7) * 8;
    const int gc0 = bn * 64 + col0;
    #pragma unroll
    for (int i = 0; i < 4; ++i) {
      const int row = (tid >> 3) * 4 + i;
      if (row < nval) {
        const size_t token = (size_t)prow[row];
        bf16x8 v = *(const bf16x8*)(SMEM + row * 136 + col0);
        *(bf16x8*)(z + token * 2048 + gc0) = v;
      }
    }
  }
}

// ---------------------------------------------------------------- flash attention, swapped QK^T
__global__ __launch_bounds__(256)
void attn_kernel(const bf16_t* __restrict__ kv, const bf16_t* __restrict__ vT,
                 bf16_t* __restrict__ hb) {
  __shared__ bf16_t Kl[64 * 64];
  __shared__ bf16_t Vl[64 * 64];
  const int tid = threadIdx.x;
  const int wave = tid >> 6, lane = tid & 63;
  const int l15 = lane & 15, l4 = lane >> 4;
  const int qt = blockIdx.x, bh = blockIdx.y;
  const int bb = bh >> 4;
  const int tok0 = bb << 10;
  const int d0 = (bh & 15) << 6;

  const int qrow = tok0 + qt * 64 + wave * 16 + l15;
  const bf16x8 bq0 = *(const bf16x8*)(hb + (size_t)qrow * 5120 + d0 + l4 * 8);
  const bf16x8 bq1 = *(const bf16x8*)(hb + (size_t)qrow * 5120 + d0 + 32 + l4 * 8);

  f32x4 o[4] = {};
  float mrun = -1e30f, lrun = 0.f;

  const int krb = tid >> 3;
  const int kss = (tid & 7) ^ (krb & 7);
  const int idx0 = ((2 * (l4 & 1) + 0) * 16 + l15) * 4;
  const int idx1 = ((2 * (l4 & 1) + 1) * 16 + l15) * 4;
  const bool hi = (l4 >> 1) != 0;

  for (int kt = 0; kt < 16; ++kt) {
    const int krow0 = tok0 + kt * 64;
    #pragma unroll
    for (int i = 0; i < 2; ++i) {
      async_copy16(Kl + (i * 256 + wave * 64) * 8,
                   kv + (size_t)(krow0 + i * 32 + krb) * 2048 + d0 + kss * 8);
      async_copy16(Vl + (i * 256 + wave * 64) * 8,
                   vT + (size_t)(bh * 64 + i * 32 + krb) * 1024 + kt * 64 + kss * 8);
    }
    __syncthreads();

    f32x4 s[4] = {};
    __builtin_amdgcn_s_setprio(1);
    #pragma unroll
    for (int ks = 0; ks < 2; ++ks) {
      const bf16x8 bq = ks ? bq1 : bq0;
      #pragma unroll
      for (int kc = 0; kc < 4; ++kc) {
        const int r = kc * 16 + l15;
        const int slot = (ks * 4 + l4) ^ (r & 7);
        bf16x8 ak = *(const bf16x8*)(Kl + r * 64 + slot * 8);
        s[kc] = __builtin_amdgcn_mfma_f32_16x16x32_bf16(ak, bq, s[kc], 0, 0, 0);
      }
    }
    __builtin_amdgcn_s_setprio(0);

    float mx = s[0][0];
    #pragma unroll
    for (int kc = 0; kc < 4; ++kc)
      #pragma unroll
      for (int r = 0; r < 4; ++r) mx = fmaxf(mx, s[kc][r]);
    mx = fmaxf(mx, __shfl_xor(mx, 16));
    mx = fmaxf(mx, __shfl_xor(mx, 32));
    mx *= 0.125f;
    const float mnew = fmaxf(mrun, mx);
    const float corr = __expf(mrun - mnew);
    float ps = 0.f;
    #pragma unroll
    for (int kc = 0; kc < 4; ++kc)
      #pragma unroll
      for (int r = 0; r < 4; ++r) {
        const float p = __expf(s[kc][r] * 0.125f - mnew);
        s[kc][r] = p;
        ps += p;
      }
    ps += __shfl_xor(ps, 16);
    ps += __shfl_xor(ps, 32);
    lrun = lrun * corr + ps;
    mrun = mnew;

    unsigned pd[4][2], bp[4][2][2];
    #pragma unroll
    for (int kc = 0; kc < 4; ++kc) {
      pd[kc][0] = pack_bf16(s[kc][0], s[kc][1]);
      pd[kc][1] = pack_bf16(s[kc][2], s[kc][3]);
    }
    #pragma unroll
    for (int kc = 0; kc < 4; ++kc)
      #pragma unroll
      for (int rp = 0; rp < 2; ++rp) {
        bp[kc][rp][0] = (unsigned)__builtin_amdgcn_ds_bpermute(idx0, (int)pd[kc][rp]);
        bp[kc][rp][1] = (unsigned)__builtin_amdgcn_ds_bpermute(idx1, (int)pd[kc][rp]);
      }
    u32x4 w0, w1;
    w0[0] = hi ? bp[1][0][0] : bp[0][0][0];
    w0[1] = hi ? bp[1][1][0] : bp[0][1][0];
    w0[2] = hi ? bp[1][0][1] : bp[0][0][1];
    w0[3] = hi ? bp[1][1][1] : bp[0][1][1];
    w1[0] = hi ? bp[3][0][0] : bp[2][0][0];
    w1[1] = hi ? bp[3][1][0] : bp[2][1][0];
    w1[2] = hi ? bp[3][0][1] : bp[2][0][1];
    w1[3] = hi ? bp[3][1][1] : bp[2][1][1];
    const bf16x8 pa0 = __builtin_bit_cast(bf16x8, w0);
    const bf16x8 pa1 = __builtin_bit_cast(bf16x8, w1);

    float cq[4];
    #pragma unroll
    for (int r = 0; r < 4; ++r) cq[r] = __shfl(corr, l4 * 4 + r);
    #pragma unroll
    for (int dn = 0; dn < 4; ++dn)
      #pragma unroll
      for (int r = 0; r < 4; ++r) o[dn][r] *= cq[r];

    __builtin_amdgcn_s_setprio(1);
    #pragma unroll
    for (int dn = 0; dn < 4; ++dn) {
      const int r = dn * 16 + l15;
      bf16x8 bv0 = *(const bf16x8*)(Vl + r * 64 + ((l4 ^ (r & 7)) * 8));
      bf16x8 bv1 = *(const bf16x8*)(Vl + r * 64 + (((4 + l4) ^ (r & 7)) * 8));
      o[dn] = __builtin_amdgcn_mfma_f32_16x16x32_bf16(pa0, bv0, o[dn], 0, 0, 0);
      o[dn] = __builtin_amdgcn_mfma_f32_16x16x32_bf16(pa1, bv1, o[dn], 0, 0, 0);
    }
    __builtin_amdgcn_s_setprio(0);
    __syncthreads();
  }

  const float il = 1.0f / lrun;
  float linv[4];
  #pragma unroll
  for (int r = 0; r < 4; ++r) linv[r] = __shfl(il, l4 * 4 + r);
  #pragma unroll
  for (int r = 0; r < 4; ++r) {
    const int gq = tok0 + qt * 64 + wave * 16 + l4 * 4 + r;
    #pragma unroll
    for (int dn = 0; dn < 4; ++dn)
      hb[(size_t)gq * 5120 + d0 + dn * 16 + l15] = (bf16_t)(o[dn][r] * linv[r]);
  }
}

// ---------------------------------------------------------------- final combine + tuple outputs
__global__ __launch_bounds__(256)
void final_kernel(const bf16_t* __restrict__ z, const float* __restrict__ x,
                  const int* __restrict__ em, const float* __restrict__ rp,
                  const float* __restrict__ alpha, float* __restrict__ out) {
  const int row = blockIdx.x, tid = threadIdx.x;
  const int e = em[row];
  const int dout = 2048 >> (3 - e);
  const float f = alpha[0] * rp[row * 4 + e] + 1.0f;
  const bf16x4 z0 = ((const bf16x4*)(z + (size_t)row * 2048))[tid];
  const bf16x4 z1 = ((const bf16x4*)(z + (size_t)row * 2048 + 1024))[tid];
  const float4 xv = ((const float4*)(x + (size_t)row * 1024))[tid];
  const int c = tid * 4;
  float4 o;
  o.x = ((c + 0) < dout ? (float)z0[0] : 0.f) + xv.x + f * ((1024 + c + 0) < dout ? (float)z1[0] : 0.f);
  o.y = ((c + 1) < dout ? (float)z0[1] : 0.f) + xv.y + f * ((1024 + c + 1) < dout ? (float)z1[1] : 0.f);
  o.z = ((c + 2) < dout ? (float)z0[2] : 0.f) + xv.z + f * ((1024 + c + 2) < dout ? (float)z1[2] : 0.f);
  o.w = ((c + 3) < dout ? (float)z0[3] : 0.f) + xv.w + f * ((1024 + c + 3) < dout ? (float)z1[3] : 0.f);
  ((float4*)(out + (size_t)row * 1024))[tid] = o;
  float* out_em = out + 8388608;
  float* out_rp = out_em + 8192;
  if (tid == 0) out_em[row] = (float)e;
  if (tid < 4) out_rp[row * 4 + tid] = rp[row * 4 + tid];
}

// ---------------------------------------------------------------- launch
extern "C" void kernel_launch(void* const* d_in, const int* in_sizes, int n_in,
                              void* d_out, int out_size, void* d_ws, size_t ws_size,
                              hipStream_t stream) {
  const float* x = (const float*)d_in[0];
  const int* em = (const int*)d_in[1];
  const float* rp = (const float*)d_in[2];
  const float* w_exp = (const float*)d_in[3];
  const float* mlp_bias = (const float*)d_in[4];
  const float* w_con = (const float*)d_in[5];
  const float* c_bias = (const float*)d_in[6];
  const float* n1g = (const float*)d_in[7];
  const float* n1b = (const float*)d_in[8];
  const float* n2g = (const float*)d_in[9];
  const float* n2b = (const float*)d_in[10];
  const float* alpha = (const float*)d_in[11];

  char* ws = (char*)d_ws;
  // layout (bytes), total 186,646,528:
  //   0          Wexp bf16 (14,680,064)
  //   14,680,064 xn bf16 (16,777,216) -> vT bf16 [128 bh][64 d][1024 tok] (attn)
  //   31,457,280 perm (32,768); t1 @ +32,768 (816B); j2 @ +34,816 (40,960B)
  //   48,234,496 kv bf16 (33,554,432) -> z bf16 [8192][2048] (gemm2)
  //   81,788,928 Wcon bf16 (20,971,520)
  //  102,760,448 hb bf16 [8192x5120]: cols 0-1023 q -> attn_out, 1024-5119 gelu(mlp)
  bf16_t* Wexp = (bf16_t*)ws;
  bf16_t* xn   = (bf16_t*)(ws + 14680064);
  bf16_t* vT   = (bf16_t*)(ws + 14680064);
  int*    perm = (int*)(ws + 31457280);
  int*    t1d  = (int*)(ws + 31457280 + 32768);
  int*    j2d  = (int*)(ws + 31457280 + 34816);
  bf16_t* kvb  = (bf16_t*)(ws + 48234496);
  bf16_t* z    = (bf16_t*)(ws + 48234496);
  bf16_t* Wcon = (bf16_t*)(ws + 81788928);
  bf16_t* hb   = (bf16_t*)(ws + 102760448);

  sort_kernel<<<1, 1024, 0, stream>>>(em, perm, t1d, j2d);
  cast_kernel<<<7168, 256, 0, stream>>>(w_exp, Wexp, 7340032);
  cast_kernel<<<10240, 256, 0, stream>>>(w_con, Wcon, 10485760);
  ln1_kernel<<<8192, 256, 0, stream>>>(x, n1g, n1b, em, xn);
  gemm_bt<0><<<dim3(56, MAXT1), 256, 0, stream>>>(xn, Wexp, perm, t1d, mlp_bias,
                                                  hb, kvb, nullptr);
  ln2_kernel<<<8192, 256, 0, stream>>>(kvb, n2g, n2b);
  vt_kernel<<<dim3(128, 16), 256, 0, stream>>>(kvb, vT);
  attn_kernel<<<dim3(16, 128), 256, 0, stream>>>(kvb, vT, hb);
  gemm_bt<1><<<MAXJ2, 256, 0, stream>>>(hb, Wcon, perm, j2d, c_bias,
                                        nullptr, nullptr, z);
  final_kernel<<<8192, 256, 0, stream>>>(z, x, em, rp, alpha, (float*)d_out);
}